// Round 1
// 4091.109 us; speedup vs baseline: 1.0944x; 1.0944x over previous
//
#include <hip/hip_runtime.h>
#include <math.h>

#define NN 500000
#define NE 16000000
#define NBKT 1954                 // ceil(NN/256): bucket = dst >> 8
#define PB2 65536                 // edges per partition block (4x bigger: longer runs per bucket)
#define NPB2 ((NE + PB2 - 1) / PB2)   // 245
#define BKT_CAP 9216              // lambda=8192, +11 sigma

// ---------------- phase 1: bucket histogram ----------------
__global__ __launch_bounds__(1024) void hist_kernel(const int4* __restrict__ dst4,
                                                    int* __restrict__ bcnt) {
    __shared__ int lh[NBKT];
    for (int i = threadIdx.x; i < NBKT; i += 1024) lh[i] = 0;
    __syncthreads();
    long base4 = (long)blockIdx.x * (PB2 / 4);
    for (int k = 0; k < PB2 / 4; k += 1024) {
        long i4 = base4 + k + threadIdx.x;
        if (i4 < NE / 4) {
            int4 d = dst4[i4];
            atomicAdd(&lh[d.x >> 8], 1);
            atomicAdd(&lh[d.y >> 8], 1);
            atomicAdd(&lh[d.z >> 8], 1);
            atomicAdd(&lh[d.w >> 8], 1);
        }
    }
    __syncthreads();
    for (int i = threadIdx.x; i < NBKT; i += 1024) {
        int c = lh[i];
        if (c) atomicAdd(&bcnt[i], c);
    }
}

// ---------------- phase 2: exclusive scan of bucket counts ----------------
__global__ __launch_bounds__(256) void scan_buckets(int* __restrict__ bcnt,
                                                    int* __restrict__ bbase) {
    __shared__ int sh[256];
    __shared__ int carry_sh;
    if (threadIdx.x == 0) carry_sh = 0;
    __syncthreads();
    for (int base = 0; base < NBKT; base += 256) {
        int i = base + threadIdx.x;
        int v = (i < NBKT) ? bcnt[i] : 0;
        sh[threadIdx.x] = v;
        __syncthreads();
        for (int off = 1; off < 256; off <<= 1) {
            int t = (threadIdx.x >= off) ? sh[threadIdx.x - off] : 0;
            __syncthreads();
            sh[threadIdx.x] += t;
            __syncthreads();
        }
        int incl = sh[threadIdx.x];
        int c = carry_sh;
        __syncthreads();
        if (i < NBKT) {
            int ex = c + incl - v;
            bbase[i] = ex;
            bcnt[i] = ex;
        }
        if (threadIdx.x == 255) carry_sh = c + incl;
        __syncthreads();
    }
    if (threadIdx.x == 0) bbase[NBKT] = NE;
}

// ---------------- phase 3: partition edges into buckets ----------------
// ebuf[pos] = (dst&255)<<19 | src   (src < 2^19, dlo < 2^8)
// 64K edges/block -> ~33.5-edge (134B) runs per bucket per block: mostly
// full-line writes instead of the 34B runs that caused 7.75x write amp.
__global__ __launch_bounds__(1024) void partition_kernel(const int4* __restrict__ src4,
                                                         const int4* __restrict__ dst4,
                                                         int* __restrict__ bcur,
                                                         int* __restrict__ ebuf) {
    __shared__ int lh[NBKT];
    for (int i = threadIdx.x; i < NBKT; i += 1024) lh[i] = 0;
    __syncthreads();
    long base4 = (long)blockIdx.x * (PB2 / 4);
    for (int k = 0; k < PB2 / 4; k += 1024) {
        long i4 = base4 + k + threadIdx.x;
        if (i4 < NE / 4) {
            int4 d = dst4[i4];
            atomicAdd(&lh[d.x >> 8], 1);
            atomicAdd(&lh[d.y >> 8], 1);
            atomicAdd(&lh[d.z >> 8], 1);
            atomicAdd(&lh[d.w >> 8], 1);
        }
    }
    __syncthreads();
    for (int i = threadIdx.x; i < NBKT; i += 1024) {
        int c = lh[i];
        if (c) lh[i] = atomicAdd(&bcur[i], c);   // reserve run; lh becomes cursor
    }
    __syncthreads();
    for (int k = 0; k < PB2 / 4; k += 1024) {
        long i4 = base4 + k + threadIdx.x;
        if (i4 < NE / 4) {
            int4 d = dst4[i4];
            int4 s = src4[i4];
            int pos;
            pos = atomicAdd(&lh[d.x >> 8], 1); ebuf[pos] = ((d.x & 255) << 19) | s.x;
            pos = atomicAdd(&lh[d.y >> 8], 1); ebuf[pos] = ((d.y & 255) << 19) | s.y;
            pos = atomicAdd(&lh[d.z >> 8], 1); ebuf[pos] = ((d.z & 255) << 19) | s.z;
            pos = atomicAdd(&lh[d.w >> 8], 1); ebuf[pos] = ((d.w & 255) << 19) | s.w;
        }
    }
}

// ---------------- phase 4: per-bucket CSR build ----------------
// Counting-sort scatter goes into LDS (outb), then streamed out coalesced —
// removes the random-4B-write RMW traffic of the in-place version.
__global__ __launch_bounds__(256) void bucket_csr(const int* __restrict__ bbase,
                                                  int* __restrict__ ebuf,   // == csr, in place
                                                  int* __restrict__ rp,
                                                  float* __restrict__ dis) {
    __shared__ int eds[BKT_CAP];
    __shared__ int outb[BKT_CAP];
    __shared__ int cnt[256];
    __shared__ int scn[256];
    int b = blockIdx.x;
    int ebase = bbase[b];
    int nb = bbase[b + 1] - ebase;
    if (nb > BKT_CAP) nb = BKT_CAP;   // statistically impossible; guards LDS
    for (int i = threadIdx.x; i < nb; i += 256) eds[i] = ebuf[ebase + i];
    cnt[threadIdx.x] = 0;
    __syncthreads();
    for (int i = threadIdx.x; i < nb; i += 256) atomicAdd(&cnt[eds[i] >> 19], 1);
    __syncthreads();
    int my = cnt[threadIdx.x];
    scn[threadIdx.x] = my;
    __syncthreads();
    for (int off = 1; off < 256; off <<= 1) {
        int t = (threadIdx.x >= off) ? scn[threadIdx.x - off] : 0;
        __syncthreads();
        scn[threadIdx.x] += t;
        __syncthreads();
    }
    int excl = scn[threadIdx.x] - my;
    int v = b * 256 + threadIdx.x;
    if (v < NN) {
        rp[v] = ebase + excl;
        dis[v] = rsqrtf((float)(my + 1));       // +1 self loop
    }
    __syncthreads();
    cnt[threadIdx.x] = excl;                    // reuse as running cursor
    __syncthreads();
    for (int i = threadIdx.x; i < nb; i += 256) {
        int p = eds[i];
        int pos = atomicAdd(&cnt[p >> 19], 1);
        outb[pos] = p & 0x7FFFF;                // scatter in LDS, not global
    }
    __syncthreads();
    for (int i = threadIdx.x; i < nb; i += 256) ebuf[ebase + i] = outb[i];  // coalesced
    if (b == 0 && threadIdx.x == 0) rp[NN] = NE;
}

__global__ void init_z(const float* __restrict__ x0, const float* __restrict__ dis,
                       float* __restrict__ z) {
    int i = blockIdx.x * 256 + threadIdx.x;
    if (i < NN) z[i] = x0[i] * dis[i];
}

// ---------------- per-layer SpMV (CSR-vector, 8 lanes/row) ----------------
// h[v] = dis[v] * (sum_{e in in(v)} z[src_e] + z[v]);  y = (0.7h + 0.3 x0)*w
// act: 0=none 1=relu 2=leaky(0.01) 3=sigmoid 4=final(n*sigmoid -> int)
// Gather loop is hand-batched 4-wide: the naive form is a serial
// csr-load -> z-gather dependent chain (MLP=1, latency-bound at ~4 iters).
// Batching issues 4 independent csr loads then 4 independent gathers.
// Per-lane summation order is unchanged (j, j+8, j+16, j+24) -> bit-identical.
__global__ __launch_bounds__(256) void layer_kernel(
        const int* __restrict__ rp, const int* __restrict__ csr,
        const float* __restrict__ zin, const float* __restrict__ dis,
        const float* __restrict__ x0, const float* __restrict__ w,
        int li, int act, float* __restrict__ zout, int* __restrict__ out) {
    int tid = blockIdx.x * 256 + threadIdx.x;
    int v = tid >> 3;                                   // 8 lanes per row; grid exact
    int lane = threadIdx.x & 7;
    int beg = rp[v];
    int end = rp[v + 1];
    float s = 0.f;
    int j = beg + lane;
    for (; j + 24 < end; j += 32) {
        int c0 = csr[j];
        int c1 = csr[j + 8];
        int c2 = csr[j + 16];
        int c3 = csr[j + 24];
        float z0 = zin[c0];
        float z1 = zin[c1];
        float z2 = zin[c2];
        float z3 = zin[c3];
        s += z0; s += z1; s += z2; s += z3;
    }
    for (; j < end; j += 8) s += zin[csr[j]];
    s += __shfl_xor(s, 1);
    s += __shfl_xor(s, 2);
    s += __shfl_xor(s, 4);
    if (lane != 0) return;
    s += zin[v];                                        // self loop
    float h = dis[v] * s;
    float comb = 0.7f * h + 0.3f * x0[v];
    float y = comb * w[li];
    if (act == 4) {
        float sg = 1.f / (1.f + expf(-y));
        out[v] = (int)(500000.f * sg);
        return;
    }
    float r;
    if (act == 0)      r = y;
    else if (act == 1) r = fmaxf(y, 0.f);
    else if (act == 2) r = (y > 0.f) ? y : 0.01f * y;
    else               r = 1.f / (1.f + expf(-y));      // sigmoid
    zout[v] = dis[v] * r;
}

// ---------------- launch ----------------
extern "C" void kernel_launch(void* const* d_in, const int* in_sizes, int n_in,
                              void* d_out, int out_size, void* d_ws, size_t ws_size,
                              hipStream_t stream) {
    const float* x0  = (const float*)d_in[0];
    const float* w   = (const float*)d_in[1];
    const int*   adj = (const int*)d_in[2];             // int32 (jax demotes int64)
    const int*   src = adj;
    const int*   dst = adj + NE;
    int* out = (int*)d_out;

    uintptr_t p = (uintptr_t)d_ws;
    auto alloc = [&](size_t bytes) -> void* {
        p = (p + 255) & ~(uintptr_t)255;
        void* r = (void*)p;
        p += bytes;
        return r;
    };
    float* dis   = (float*)alloc((size_t)NN * 4);
    int*   rp    = (int*)alloc((size_t)(NN + 1) * 4);
    float* z0    = (float*)alloc((size_t)NN * 4);
    float* z1    = (float*)alloc((size_t)NN * 4);
    int*   bcnt  = (int*)alloc((size_t)NBKT * 4);       // counts -> partition cursor
    int*   bbase = (int*)alloc((size_t)(NBKT + 1) * 4);
    int*   csr   = (int*)alloc((size_t)NE * 4);         // ebuf, rebuilt in place
    (void)ws_size;

    hipMemsetAsync(bcnt, 0, (size_t)NBKT * 4, stream);

    hist_kernel<<<NPB2, 1024, 0, stream>>>((const int4*)dst, bcnt);
    scan_buckets<<<1, 256, 0, stream>>>(bcnt, bbase);
    partition_kernel<<<NPB2, 1024, 0, stream>>>((const int4*)src, (const int4*)dst, bcnt, csr);
    bucket_csr<<<NBKT, 256, 0, stream>>>(bbase, csr, rp, dis);
    init_z<<<(NN + 255) / 256, 256, 0, stream>>>(x0, dis, z0);

    float* zbuf[2] = {z0, z1};
    const int LB = (NN * 8) / 256;                      // 15625, exact
    for (int i = 0; i < 49; i++) {
        int act;
        if (i == 0)            act = 0;
        else if (i == 48)      act = 4;
        else if (i % 10 == 1)  act = 2;                 // leaky {1,11,21,31,41}
        else if (i % 10 == 4)  act = 3;                 // sigmoid {4,14,24,34,44}
        else                   act = 1;                 // relu
        layer_kernel<<<LB, 256, 0, stream>>>(rp, csr, zbuf[i & 1], dis, x0, w,
                                             i, act, zbuf[(i + 1) & 1], out);
    }
}

// Round 2
// 4054.152 us; speedup vs baseline: 1.1043x; 1.0091x over previous
//
#include <hip/hip_runtime.h>
#include <math.h>

#define NN 500000
#define NE 16000000
#define BSH 9                     // bucket = dst >> 9  (512 nodes per bucket)
#define NBKT 977                  // ceil(NN/512)
#define PB2 65536                 // edges per partition block
#define NPB2 ((NE + PB2 - 1) / PB2)   // 245
#define BKT_CAP 17920             // mean 16384, +12 sigma

// ---------------- phase 1: bucket histogram ----------------
__global__ __launch_bounds__(1024) void hist_kernel(const int4* __restrict__ dst4,
                                                    int* __restrict__ bcnt) {
    __shared__ int lh[NBKT];
    for (int i = threadIdx.x; i < NBKT; i += 1024) lh[i] = 0;
    __syncthreads();
    long base4 = (long)blockIdx.x * (PB2 / 4);
    for (int k = 0; k < PB2 / 4; k += 1024) {
        long i4 = base4 + k + threadIdx.x;
        if (i4 < NE / 4) {
            int4 d = dst4[i4];
            atomicAdd(&lh[d.x >> BSH], 1);
            atomicAdd(&lh[d.y >> BSH], 1);
            atomicAdd(&lh[d.z >> BSH], 1);
            atomicAdd(&lh[d.w >> BSH], 1);
        }
    }
    __syncthreads();
    for (int i = threadIdx.x; i < NBKT; i += 1024) {
        int c = lh[i];
        if (c) atomicAdd(&bcnt[i], c);
    }
}

// ---------------- phase 2: exclusive scan of bucket counts ----------------
__global__ __launch_bounds__(256) void scan_buckets(int* __restrict__ bcnt,
                                                    int* __restrict__ bbase) {
    __shared__ int sh[256];
    __shared__ int carry_sh;
    if (threadIdx.x == 0) carry_sh = 0;
    __syncthreads();
    for (int base = 0; base < NBKT; base += 256) {
        int i = base + threadIdx.x;
        int v = (i < NBKT) ? bcnt[i] : 0;
        sh[threadIdx.x] = v;
        __syncthreads();
        for (int off = 1; off < 256; off <<= 1) {
            int t = (threadIdx.x >= off) ? sh[threadIdx.x - off] : 0;
            __syncthreads();
            sh[threadIdx.x] += t;
            __syncthreads();
        }
        int incl = sh[threadIdx.x];
        int c = carry_sh;
        __syncthreads();
        if (i < NBKT) {
            int ex = c + incl - v;
            bbase[i] = ex;
            bcnt[i] = ex;
        }
        if (threadIdx.x == 255) carry_sh = c + incl;
        __syncthreads();
    }
    if (threadIdx.x == 0) bbase[NBKT] = NE;
}

// ---------------- phase 3: partition edges into buckets ----------------
// ebuf[pos] = (dst&511)<<19 | src   (src < 2^19, dlo < 2^9)
// 977 buckets: open-line footprint per XCD = ~31 blocks * 977 lines * 64B
// = 1.9MB < 4MB L2, so partial lines survive until their run completes.
__global__ __launch_bounds__(1024) void partition_kernel(const int4* __restrict__ src4,
                                                         const int4* __restrict__ dst4,
                                                         int* __restrict__ bcur,
                                                         int* __restrict__ ebuf) {
    __shared__ int lh[NBKT];
    for (int i = threadIdx.x; i < NBKT; i += 1024) lh[i] = 0;
    __syncthreads();
    long base4 = (long)blockIdx.x * (PB2 / 4);
    for (int k = 0; k < PB2 / 4; k += 1024) {
        long i4 = base4 + k + threadIdx.x;
        if (i4 < NE / 4) {
            int4 d = dst4[i4];
            atomicAdd(&lh[d.x >> BSH], 1);
            atomicAdd(&lh[d.y >> BSH], 1);
            atomicAdd(&lh[d.z >> BSH], 1);
            atomicAdd(&lh[d.w >> BSH], 1);
        }
    }
    __syncthreads();
    for (int i = threadIdx.x; i < NBKT; i += 1024) {
        int c = lh[i];
        if (c) lh[i] = atomicAdd(&bcur[i], c);   // reserve run; lh becomes cursor
    }
    __syncthreads();
    for (int k = 0; k < PB2 / 4; k += 1024) {
        long i4 = base4 + k + threadIdx.x;
        if (i4 < NE / 4) {
            int4 d = dst4[i4];
            int4 s = src4[i4];
            int pos;
            pos = atomicAdd(&lh[d.x >> BSH], 1); ebuf[pos] = ((d.x & 511) << 19) | s.x;
            pos = atomicAdd(&lh[d.y >> BSH], 1); ebuf[pos] = ((d.y & 511) << 19) | s.y;
            pos = atomicAdd(&lh[d.z >> BSH], 1); ebuf[pos] = ((d.z & 511) << 19) | s.z;
            pos = atomicAdd(&lh[d.w >> BSH], 1); ebuf[pos] = ((d.w & 511) << 19) | s.w;
        }
    }
}

// ---------------- phase 4: per-bucket CSR build ----------------
// 512-node buckets, 512 threads. LDS: eds+outb = 144KB (1 block/CU).
// Also fuses init_z (z0 = x0*dis).
__global__ __launch_bounds__(512) void bucket_csr(const int* __restrict__ bbase,
                                                  int* __restrict__ ebuf,   // == csr, in place
                                                  int* __restrict__ rp,
                                                  float* __restrict__ dis,
                                                  const float* __restrict__ x0,
                                                  float* __restrict__ z0) {
    __shared__ int eds[BKT_CAP];
    __shared__ int outb[BKT_CAP];
    __shared__ int cnt[512];
    __shared__ int scn[512];
    int b = blockIdx.x;
    int ebase = bbase[b];
    int nb = bbase[b + 1] - ebase;
    if (nb > BKT_CAP) nb = BKT_CAP;   // statistically impossible; guards LDS
    for (int i = threadIdx.x; i < nb; i += 512) eds[i] = ebuf[ebase + i];
    cnt[threadIdx.x] = 0;
    __syncthreads();
    for (int i = threadIdx.x; i < nb; i += 512) atomicAdd(&cnt[eds[i] >> 19], 1);
    __syncthreads();
    int my = cnt[threadIdx.x];
    scn[threadIdx.x] = my;
    __syncthreads();
    for (int off = 1; off < 512; off <<= 1) {
        int t = (threadIdx.x >= off) ? scn[threadIdx.x - off] : 0;
        __syncthreads();
        scn[threadIdx.x] += t;
        __syncthreads();
    }
    int excl = scn[threadIdx.x] - my;
    int v = b * 512 + threadIdx.x;
    if (v < NN) {
        rp[v] = ebase + excl;
        float dv = rsqrtf((float)(my + 1));     // +1 self loop
        dis[v] = dv;
        z0[v] = x0[v] * dv;
    }
    __syncthreads();
    cnt[threadIdx.x] = excl;                    // reuse as running cursor
    __syncthreads();
    for (int i = threadIdx.x; i < nb; i += 512) {
        int p = eds[i];
        int pos = atomicAdd(&cnt[p >> 19], 1);
        outb[pos] = p & 0x7FFFF;                // scatter in LDS, not global
    }
    __syncthreads();
    for (int i = threadIdx.x; i < nb; i += 512) ebuf[ebase + i] = outb[i];  // coalesced
    if (b == 0 && threadIdx.x == 0) rp[NN] = NE;
}

// ---------------- per-layer SpMV (CSR-vector, 8 lanes/row) ----------------
// h[v] = dis[v] * (sum_{e in in(v)} z[src_e] + z[v]);  y = (0.7h + 0.3 x0)*w
// act: 0=none 1=relu 2=leaky(0.01) 3=sigmoid 4=final(n*sigmoid -> int)
// Gathers use agent-scope relaxed atomic loads -> global_load_dword sc0,
// bypassing L1: the random 4B gathers are L1 misses anyway, and the L1
// line-fill machinery (limited outstanding misses @ ~200cy L2 latency)
// is the theorized throughput cap. NOT nontemporal: z must stay in L2.
// Summation order unchanged -> bit-identical numerics.
__global__ __launch_bounds__(256) void layer_kernel(
        const int* __restrict__ rp, const int* __restrict__ csr,
        const float* __restrict__ zin, const float* __restrict__ dis,
        const float* __restrict__ x0, const float* __restrict__ w,
        int li, int act, float* __restrict__ zout, int* __restrict__ out) {
    int tid = blockIdx.x * 256 + threadIdx.x;
    int v = tid >> 3;                                   // 8 lanes per row; grid exact
    int lane = threadIdx.x & 7;
    int beg = rp[v];
    int end = rp[v + 1];
    float s = 0.f;
    int j = beg + lane;
    for (; j + 24 < end; j += 32) {
        int c0 = csr[j];
        int c1 = csr[j + 8];
        int c2 = csr[j + 16];
        int c3 = csr[j + 24];
        float z0 = __hip_atomic_load(&zin[c0], __ATOMIC_RELAXED, __HIP_MEMORY_SCOPE_AGENT);
        float z1 = __hip_atomic_load(&zin[c1], __ATOMIC_RELAXED, __HIP_MEMORY_SCOPE_AGENT);
        float z2 = __hip_atomic_load(&zin[c2], __ATOMIC_RELAXED, __HIP_MEMORY_SCOPE_AGENT);
        float z3 = __hip_atomic_load(&zin[c3], __ATOMIC_RELAXED, __HIP_MEMORY_SCOPE_AGENT);
        s += z0; s += z1; s += z2; s += z3;
    }
    for (; j < end; j += 8)
        s += __hip_atomic_load(&zin[csr[j]], __ATOMIC_RELAXED, __HIP_MEMORY_SCOPE_AGENT);
    s += __shfl_xor(s, 1);
    s += __shfl_xor(s, 2);
    s += __shfl_xor(s, 4);
    if (lane != 0) return;
    s += zin[v];                                        // self loop (8 consecutive v: L1-friendly)
    float h = dis[v] * s;
    float comb = 0.7f * h + 0.3f * x0[v];
    float y = comb * w[li];
    if (act == 4) {
        float sg = 1.f / (1.f + expf(-y));
        out[v] = (int)(500000.f * sg);
        return;
    }
    float r;
    if (act == 0)      r = y;
    else if (act == 1) r = fmaxf(y, 0.f);
    else if (act == 2) r = (y > 0.f) ? y : 0.01f * y;
    else               r = 1.f / (1.f + expf(-y));      // sigmoid
    zout[v] = dis[v] * r;
}

// ---------------- launch ----------------
extern "C" void kernel_launch(void* const* d_in, const int* in_sizes, int n_in,
                              void* d_out, int out_size, void* d_ws, size_t ws_size,
                              hipStream_t stream) {
    const float* x0  = (const float*)d_in[0];
    const float* w   = (const float*)d_in[1];
    const int*   adj = (const int*)d_in[2];             // int32 (jax demotes int64)
    const int*   src = adj;
    const int*   dst = adj + NE;
    int* out = (int*)d_out;

    uintptr_t p = (uintptr_t)d_ws;
    auto alloc = [&](size_t bytes) -> void* {
        p = (p + 255) & ~(uintptr_t)255;
        void* r = (void*)p;
        p += bytes;
        return r;
    };
    float* dis   = (float*)alloc((size_t)NN * 4);
    int*   rp    = (int*)alloc((size_t)(NN + 1) * 4);
    float* z0    = (float*)alloc((size_t)NN * 4);
    float* z1    = (float*)alloc((size_t)NN * 4);
    int*   bcnt  = (int*)alloc((size_t)NBKT * 4);       // counts -> partition cursor
    int*   bbase = (int*)alloc((size_t)(NBKT + 1) * 4);
    int*   csr   = (int*)alloc((size_t)NE * 4);         // ebuf, rebuilt in place
    (void)ws_size;

    hipMemsetAsync(bcnt, 0, (size_t)NBKT * 4, stream);

    hist_kernel<<<NPB2, 1024, 0, stream>>>((const int4*)dst, bcnt);
    scan_buckets<<<1, 256, 0, stream>>>(bcnt, bbase);
    partition_kernel<<<NPB2, 1024, 0, stream>>>((const int4*)src, (const int4*)dst, bcnt, csr);
    bucket_csr<<<NBKT, 512, 0, stream>>>(bbase, csr, rp, dis, x0, z0);

    float* zbuf[2] = {z0, z1};
    const int LB = (NN * 8) / 256;                      // 15625, exact
    for (int i = 0; i < 49; i++) {
        int act;
        if (i == 0)            act = 0;
        else if (i == 48)      act = 4;
        else if (i % 10 == 1)  act = 2;                 // leaky {1,11,21,31,41}
        else if (i % 10 == 4)  act = 3;                 // sigmoid {4,14,24,34,44}
        else                   act = 1;                 // relu
        layer_kernel<<<LB, 256, 0, stream>>>(rp, csr, zbuf[i & 1], dis, x0, w,
                                             i, act, zbuf[(i + 1) & 1], out);
    }
}